// Round 14
// baseline (74.983 us; speedup 1.0000x reference)
//
#include <hip/hip_runtime.h>
#include <hip/hip_bf16.h>

// Problem sizes (fixed by reference)
#define B_   4
#define T_   2048
#define D_   512
#define H_   8
#define DH_  64
#define BT_  (B_*T_)          // 8192
#define N3D_ (3*D_)           // 1536

typedef __bf16  bf16x8 __attribute__((ext_vector_type(8)));
typedef float   f32x4  __attribute__((ext_vector_type(4)));
typedef short   short8 __attribute__((ext_vector_type(8)));
typedef unsigned short u16;

#if defined(__has_builtin)
#if __has_builtin(__builtin_amdgcn_exp2f)
#define EXP2_OK 1
#endif
#endif
#ifndef EXP2_OK
#define EXP2_OK 0
#endif

#if EXP2_OK
#define QSCALE_F (0.125f * 1.44269504088896340736f)
static __device__ __forceinline__ float fastexp(float x) { return __builtin_amdgcn_exp2f(x); }
#else
#define QSCALE_F (0.125f)
static __device__ __forceinline__ float fastexp(float x) { return __expf(x); }
#endif

static __device__ __forceinline__ f32x4 fzero() { f32x4 z = {0.f,0.f,0.f,0.f}; return z; }

static __device__ __forceinline__ f32x4 mfma16(short8 a, short8 b, f32x4 c) {
  return __builtin_amdgcn_mfma_f32_16x16x32_bf16(
      __builtin_bit_cast(bf16x8, a), __builtin_bit_cast(bf16x8, b), c, 0, 0, 0);
}

// XOR swizzle for [row][128B] LDS tiles (128^2 gemm + attn kernels).
static __device__ __forceinline__ int swz(int byteoff) {
  return byteoff ^ (((byteoff >> 7) & 7) << 4);
}

static __device__ __forceinline__ u16 bf16bits(float f) {
  __hip_bfloat16 h = __float2bfloat16(f);
  return *reinterpret_cast<u16*>(&h);
}

// async global->LDS DMA, 16B per lane. lds dest must be wave-uniform base
// (HW writes base + lane*16); global src is per-lane.
static __device__ __forceinline__ void gld_lds16(const void* g, void* l) {
  __builtin_amdgcn_global_load_lds(
      (const __attribute__((address_space(1))) void*)g,
      (__attribute__((address_space(3))) void*)l, 16, 0, 0);
}

template <int N>
static __device__ __forceinline__ void vwait() {
  asm volatile("s_waitcnt vmcnt(%0)" :: "i"(N) : "memory");
}

// ---------------------------------------------------------------------------
// Kernel 1 (fused prep): blocks [0,768): x -> bf16 (vectorized x8);
// blocks [768,960): wqkv LDS-tile transpose; [960,1024): wout transpose.
// ---------------------------------------------------------------------------
#define XBLKS 768
__global__ __launch_bounds__(256) void prep_kernel(
    const float* __restrict__ x, const float* __restrict__ wqkv,
    const float* __restrict__ wout,
    u16* __restrict__ xb, u16* __restrict__ wqkvT, u16* __restrict__ woutT) {
  __shared__ u16 lt[64 * 72];  // 64x64 bf16 tile, padded row stride 72
  const int tid = threadIdx.x;
  const int blk = blockIdx.x;

  if (blk < XBLKS) {
    const float4* x4 = reinterpret_cast<const float4*>(x);
    for (int idx = blk * 256 + tid; idx < BT_*D_/8; idx += XBLKS * 256) {
      float4 a = x4[idx*2], b = x4[idx*2+1];
      short8 o;
      o[0] = (short)bf16bits(a.x); o[1] = (short)bf16bits(a.y);
      o[2] = (short)bf16bits(a.z); o[3] = (short)bf16bits(a.w);
      o[4] = (short)bf16bits(b.x); o[5] = (short)bf16bits(b.y);
      o[6] = (short)bf16bits(b.z); o[7] = (short)bf16bits(b.w);
      *reinterpret_cast<short8*>(&xb[idx*8]) = o;
    }
    return;
  }

  // weight transpose: source (K=512, N) row-major -> dest (N, K=512) bf16
  int wb = blk - XBLKS;
  const float* src;
  u16* dst;
  int srcld, k0, n0;
  if (wb < 192) {                 // wqkv: 8 K-tiles x 24 N-tiles
    src = wqkv; dst = wqkvT; srcld = N3D_;
    k0 = (wb & 7) * 64; n0 = (wb >> 3) * 64;
  } else {                        // wout: 8 x 8
    wb -= 192;
    src = wout; dst = woutT; srcld = D_;
    k0 = (wb & 7) * 64; n0 = (wb >> 3) * 64;
  }
  {
    int c = tid & 63, r0 = tid >> 6;
#pragma unroll
    for (int i = 0; i < 16; ++i) {
      int r = r0 * 16 + i;
      lt[r * 72 + c] = bf16bits(src[(long)(k0 + r) * srcld + n0 + c]);
    }
  }
  __syncthreads();
  {
    int kc = (tid & 7) * 8;
#pragma unroll
    for (int half = 0; half < 2; ++half) {
      int n = (tid >> 3) + half * 32;
      short8 v;
#pragma unroll
      for (int j = 0; j < 8; ++j) v[j] = (short)lt[(kc + j) * 72 + n];
      *reinterpret_cast<short8*>(&dst[(long)(n0 + n) * D_ + k0 + kc]) = v;
    }
  }
}

// ---------------------------------------------------------------------------
// GEMM1 (qkv projection): C[8192][1536] = xb[8192][512] * wqkvT[1536][512]^T
// 256x256 tile, 8 waves (2M x 4N; per-wave 128x64 = 8x4 frags), BK=64.
// Half-tile pipelined schedule (8-phase family, counted vmcnt):
//  - LDS 128KB = 2 K-tile slots x 4 half-tiles (A-kh0,B-kh0,A-kh1,B-kh1; 16KB).
//  - 32 phases (4/K-tile). Phase p: stage half-tile p+5 (2 DMA loads/thread),
//    vmcnt(6) [3 half-tiles in flight, never 0 mid-loop], s_barrier,
//    8x ds_read_b128, lgkmcnt(0)+sched_barrier(0), 16 MFMA under setprio.
//  - Invariants (hand-checked): half-tile g staged at phase g-5; slot's last
//    reader finished 2 phases before staging (barrier-ordered); vmcnt(6) +
//    barrier => needed half-tiles fully landed across all waves (margin 1).
//    Tail: vmcnt 4 (p=28,29) then 0 (p=30,31).
//  - 64B LDS rows => b128 reads naturally bank-balanced (4*(lr&1)+lg), no
//    swizzle; DMA dest linear, source unpermuted.
// Epilogue: LDS re-tile (128KB free) -> coalesced short8 stores; cols
// bn*256: bn 0-1=q (scaled), 2-3=k, 4-5=v^T (transposed tile).
// ---------------------------------------------------------------------------
__global__ __launch_bounds__(512) void gemm256_kernel(
    const u16* __restrict__ A, const u16* __restrict__ Wt,
    u16* __restrict__ qbuf, u16* __restrict__ kbuf, u16* __restrict__ vtbuf) {
  // grid 192 = 32 bm x 6 bn, XCD-chunked bijective swizzle (192 % 8 == 0)
  const int lin = blockIdx.x;
  const int cpx = gridDim.x >> 3;            // 24
  const int nn = (lin & 7) * cpx + (lin >> 3);
  const int bm = nn / 6, bn = nn % 6;

  const int tid = threadIdx.x;
  const int w = tid >> 6;                    // 0..7
  const int wm = w >> 2, wn = w & 3;
  const int l = tid & 63;
  const int lr = l & 15, lg = l >> 4;

  __shared__ char ls[131072];                // [ktile&1][j:4][16KB]

  f32x4 acc[8][4];
#pragma unroll
  for (int i = 0; i < 8; ++i)
#pragma unroll
    for (int j = 0; j < 4; ++j) acc[i][j] = fzero();

  const char* Ab = reinterpret_cast<const char*>(A) + (long)bm * 256 * 1024;
  const char* Wb = reinterpret_cast<const char*>(Wt) + (long)bn * 256 * 1024;

  const int srccol = (l & 3) << 4;           // 16B col within 64B k-half row
  const int srow16 = l >> 2;                 // row within 16-row chunk
  const int colb = lg << 4;                  // read col (16B units)

  auto stageHT = [&](int g) {                // half-tile g = 4*kt + j
    const int ktg = g >> 2, j = g & 3;       // j: 0=A-kh0 1=B-kh0 2=A-kh1 3=B-kh1
    const char* src = (j & 1) ? Wb : Ab;
    char* slot = ls + ((ktg & 1) << 16) + (j << 14);
    const int kcol = ktg * 128 + ((j >> 1) << 6);
#pragma unroll
    for (int c = 0; c < 2; ++c) {
      int chunk = w * 2 + c;                 // 0..15, wave-uniform
      int r = chunk * 16 + srow16;           // 0..255
      gld_lds16(src + (long)r * 1024 + kcol + srccol, slot + chunk * 1024);
    }
  };

  // prologue: half-tiles 0..4 (kt0 complete + kt1's A-kh0)
  stageHT(0); stageHT(1); stageHT(2); stageHT(3); stageHT(4);

  for (int kt = 0; kt < 8; ++kt) {
    const char* bufb = ls + ((kt & 1) << 16);
#pragma unroll
    for (int q = 0; q < 4; ++q) {
      const int c = q >> 1, mg = q & 1;
      {
        int p5 = 4 * kt + q + 5;
        if (p5 < 32) stageHT(p5);
      }
      if (kt == 7) { if (q < 2) vwait<4>(); else vwait<0>(); }
      else vwait<6>();
      asm volatile("" ::: "memory");
      __builtin_amdgcn_s_barrier();
      asm volatile("" ::: "memory");

      const char* baseA = bufb + ((2 * c) << 14);
      const char* baseB = bufb + ((2 * c + 1) << 14);
      short8 af[4], bfr[4];
#pragma unroll
      for (int mi = 0; mi < 4; ++mi) {
        int R = wm * 128 + (mg * 4 + mi) * 16 + lr;
        af[mi] = *reinterpret_cast<const short8*>(baseA + R * 64 + colb);
      }
#pragma unroll
      for (int ni = 0; ni < 4; ++ni) {
        int R = wn * 64 + ni * 16 + lr;
        bfr[ni] = *reinterpret_cast<const short8*>(baseB + R * 64 + colb);
      }
      asm volatile("s_waitcnt lgkmcnt(0)" ::: "memory");
      __builtin_amdgcn_sched_barrier(0);
      __builtin_amdgcn_s_setprio(1);
#pragma unroll
      for (int mi = 0; mi < 4; ++mi)
#pragma unroll
        for (int ni = 0; ni < 4; ++ni)
          acc[mg * 4 + mi][ni] = mfma16(af[mi], bfr[ni], acc[mg * 4 + mi][ni]);
      __builtin_amdgcn_s_setprio(0);
    }
  }
  // all DMA retired (phase 31 drained to 0); order loop reads vs epilogue
  asm volatile("" ::: "memory");
  __builtin_amdgcn_s_barrier();
  asm volatile("" ::: "memory");

  // ---- epilogue: re-tile through LDS (128KB), coalesced short8 stores ----
  const int which = bn >> 1;                 // 0=q 1=k 2=v^T
  const int b = bm >> 3;                     // 256 rows: 2048/256 = 8 per batch
  const int tb0 = (bm & 7) * 256;
  if (which == 2) {
    // transposed tile: ls[d' 256][512B t], XOR swizzle on bits 4..6 by row
#pragma unroll
    for (int MI = 0; MI < 8; ++MI)
#pragma unroll
      for (int r = 0; r < 4; ++r) {
        int trow = wm * 128 + MI * 16 + lg * 4 + r;
#pragma unroll
        for (int ni = 0; ni < 4; ++ni) {
          int dcol = wn * 64 + ni * 16 + lr;
          int off = dcol * 512 + trow * 2;
          off ^= ((off >> 9) & 7) << 4;
          *reinterpret_cast<u16*>(ls + off) = bf16bits(acc[MI][ni][r]);
        }
      }
  } else {
    const float scale = (which == 0) ? QSCALE_F : 1.0f;
#pragma unroll
    for (int MI = 0; MI < 8; ++MI)
#pragma unroll
      for (int r = 0; r < 4; ++r) {
        int trow = wm * 128 + MI * 16 + lg * 4 + r;
#pragma unroll
        for (int ni = 0; ni < 4; ++ni) {
          int dcol = wn * 64 + ni * 16 + lr;
          int off = trow * 512 + dcol * 2;
          off ^= ((off >> 9) & 7) << 4;
          *reinterpret_cast<u16*>(ls + off) = bf16bits(acc[MI][ni][r] * scale);
        }
      }
  }
  __syncthreads();
  if (which == 2) {
    const int bnv = bn - 4;
#pragma unroll
    for (int it = 0; it < 16; ++it) {
      int dp = it * 16 + (tid >> 5);         // d' 0..255
      int tc = (tid & 31) * 16;              // byte col within 512B row
      int off = (dp * 512 + tc) ^ ((dp & 7) << 4);
      short8 v = *reinterpret_cast<const short8*>(ls + off);
      int h = bnv * 4 + (dp >> 6), d = dp & 63;
      long dst = ((long)((b * H_ + h) * DH_ + d)) * T_ + tb0 + tc / 2;
      *reinterpret_cast<short8*>(vtbuf + dst) = v;
    }
  } else {
    u16* obuf = (which == 0) ? qbuf : kbuf;
    const int bq = bn & 1;
#pragma unroll
    for (int it = 0; it < 16; ++it) {
      int trow = it * 16 + (tid >> 5);
      int tc = (tid & 31) * 16;
      int off = (trow * 512 + tc) ^ ((trow & 7) << 4);
      short8 v = *reinterpret_cast<const short8*>(ls + off);
      int dcol = tc / 2;
      int h = bq * 4 + (dcol >> 6), d = dcol & 63;
      long dst = ((long)(b * H_ + h) * T_ + tb0 + trow) * DH_ + d;
      *reinterpret_cast<short8*>(obuf + dst) = v;
    }
  }
}

// ---------------------------------------------------------------------------
// GEMM2 (unchanged r13): C[8192][512] = ao * woutT^T, 128x128 2-phase.
// Epilogue adds bias, multiplies row mask, stores f32.
// ---------------------------------------------------------------------------
__global__ __launch_bounds__(256) void gemm_kernel(
    const u16* __restrict__ A, const u16* __restrict__ Wt,
    const float* __restrict__ bias, const float* __restrict__ msk,
    float* __restrict__ out) {
  const int NBN = 4;
  const int lin = blockIdx.x;
  const int cpx = gridDim.x >> 3;
  const int nn = (lin & 7) * cpx + (lin >> 3);
  const int bm = nn / NBN, bn = nn % NBN;

  const int tid = threadIdx.x;
  const int w = tid >> 6, l = tid & 63;
  const int wr = w >> 1, wc = w & 1;
  const int lr = l & 15, lg = l >> 4;
  const int srow = l >> 3;
  const int scol = ((l & 7) ^ srow) << 4;

  __shared__ char ls[2][32768];     // [dbuf][ A 16K | B 16K ]

  f32x4 acc[4][4];
#pragma unroll
  for (int i = 0; i < 4; ++i)
#pragma unroll
    for (int j = 0; j < 4; ++j) acc[i][j] = fzero();

  const char* Ab = reinterpret_cast<const char*>(A) + (long)bm * 128 * 1024;
  const char* Wb = reinterpret_cast<const char*>(Wt) + (long)bn * 128 * 1024;

  auto stage = [&](int kt, char* dst) {
#pragma unroll
    for (int c = 0; c < 4; ++c) {
      int chunk = w * 4 + c;              // 0..15, wave-uniform
      int row = chunk * 8 + srow;         // 0..127
      gld_lds16(Ab + (long)row * 1024 + kt * 128 + scol, dst + chunk * 1024);
      gld_lds16(Wb + (long)row * 1024 + kt * 128 + scol, dst + 16384 + chunk * 1024);
    }
  };

  stage(0, ls[0]);
  asm volatile("s_waitcnt vmcnt(0)" ::: "memory");
  __builtin_amdgcn_s_barrier();

  int cur = 0;
  for (int kt = 0; kt < 8; ++kt) {
    if (kt + 1 < 8) stage(kt + 1, ls[cur ^ 1]);
    const char* lsA = ls[cur];
    const char* lsB = ls[cur] + 16384;

#pragma unroll
    for (int c = 0; c < 2; ++c) {
      short8 af[4], bfr[4];
#pragma unroll
      for (int mi = 0; mi < 4; ++mi) {
        int row = wr * 64 + mi * 16 + lr;
        af[mi] = *reinterpret_cast<const short8*>(
            lsA + swz(row * 128 + c * 64 + lg * 16));
      }
#pragma unroll
      for (int ni = 0; ni < 4; ++ni) {
        int row = wc * 64 + ni * 16 + lr;
        bfr[ni] = *reinterpret_cast<const short8*>(
            lsB + swz(row * 128 + c * 64 + lg * 16));
      }
      __builtin_amdgcn_s_setprio(1);
#pragma unroll
      for (int mi = 0; mi < 4; ++mi)
#pragma unroll
        for (int ni = 0; ni < 4; ++ni)
          acc[mi][ni] = mfma16(af[mi], bfr[ni], acc[mi][ni]);
      __builtin_amdgcn_s_setprio(0);
    }

    asm volatile("s_waitcnt vmcnt(0)" ::: "memory");
    __builtin_amdgcn_s_barrier();
    cur ^= 1;
  }

#pragma unroll
  for (int mi = 0; mi < 4; ++mi) {
#pragma unroll
    for (int r = 0; r < 4; ++r) {
      int grow = bm * 128 + wr * 64 + mi * 16 + lg * 4 + r;
#pragma unroll
      for (int ni = 0; ni < 4; ++ni) {
        int gcol = bn * 128 + wc * 64 + ni * 16 + lr;
        float o = (acc[mi][ni][r] + bias[gcol]) * msk[grow];
        out[(long)grow * D_ + gcol] = o;
      }
    }
  }
}

// ---------------------------------------------------------------------------
// Flash attention (unchanged r13): 8 waves (wq x hf), per-half dbuf DMA K/V,
// P re-layout via per-wave LDS, partial merge at end.
// ---------------------------------------------------------------------------
__global__ __launch_bounds__(512) void attn_kernel(
    const u16* __restrict__ q, const u16* __restrict__ k,
    const u16* __restrict__ vt, const float* __restrict__ msk,
    u16* __restrict__ ao) {
  const int bh = blockIdx.x;              // 0..31
  const int qt = 31 - blockIdx.y;         // biggest first
  const int b = bh >> 3, h = bh & 7;
  const int tid = threadIdx.x;
  const int w = tid >> 6;                 // 0..7
  const int wq = w & 3;                   // q sub-tile
  const int hf = w >> 2;                  // kv half
  const int l = tid & 63;
  const int lr = l & 15, lg = l >> 4;

  const float* mrow = msk + b * T_;

  unsigned long long bal = __ballot((l < 32) ? (mrow[l * 64] != 0.f) : false);
  const int nvalid = __popcll(bal);
  if (qt >= nvalid) return;
  const int nkv = (qt + 1 < nvalid) ? (qt + 1) : nvalid;
  const int nh = (nkv - hf + 1) >> 1;     // tiles for this half
  const int niter = (nkv + 1) >> 1;       // block-wide iterations

  __shared__ char lsK[2 * 2 * 64 * 128];  // [half][dbuf][8KB] = 32KB
  __shared__ char lsV[2 * 2 * 64 * 128];  // 32KB
  __shared__ char lsP[8 * 16 * 128];      // 16KB
  char* pbase = lsP + w * (16 * 128);
  char* myK = lsK + hf * 16384;
  char* myV = lsV + hf * 16384;

  const char* kb = reinterpret_cast<const char*>(k)  + (long)bh * T_ * 128;
  const char* vb = reinterpret_cast<const char*>(vt) + (long)bh * DH_ * T_ * 2;
  const char* qb = reinterpret_cast<const char*>(q);

  const int qrow0 = qt * 64 + wq * 16;

  short8 qf[2];
#pragma unroll
  for (int c = 0; c < 2; ++c)
    qf[c] = *reinterpret_cast<const short8*>(
        qb + (((long)bh * T_ + qrow0 + lr) * DH_ + c * 32 + lg * 8) * 2);

  const int srow = l >> 3;
  const int scol = ((l & 7) ^ srow) << 4;

  auto issue = [&](int kt_, int buf) {
#pragma unroll
    for (int c = 0; c < 2; ++c) {
      int chunk = wq * 2 + c;             // 0..7, wave-uniform
      int row = chunk * 8 + srow;         // 0..63
      gld_lds16(kb + ((long)kt_ * 64 + row) * 128 + scol,
                myK + buf * 8192 + chunk * 1024);
      gld_lds16(vb + (long)row * (T_ * 2) + kt_ * 128 + scol,
                myV + buf * 8192 + chunk * 1024);
    }
  };

  if (0 < nh) issue(hf, 0);

  float mrun = -__builtin_inff(), lrun = 0.f;
  f32x4 oacc[4];
#pragma unroll
  for (int g = 0; g < 4; ++g) oacc[g] = fzero();

  for (int i = 0; i < niter; ++i) {
    __syncthreads();                      // drains DMA + block sync
    if (i + 1 < nh) issue(2 * (i + 1) + hf, (i + 1) & 1);
    if (i < nh) {
      const int kt = 2 * i + hf;
      const char* lk = myK + (i & 1) * 8192;
      const char* lv = myV + (i & 1) * 8192;

      f32x4 st[4];
      __builtin_amdgcn_s_setprio(1);
#pragma unroll
      for (int ni = 0; ni < 4; ++ni) {
        short8 kf0 = *reinterpret_cast<const short8*>(
            lk + swz((ni * 16 + lr) * 128 + lg * 16));
        short8 kf1 = *reinterpret_cast<const short8*>(
            lk + swz((ni * 16 + lr) * 128 + 64 + lg * 16));
        f32x4 z = fzero();
        z = mfma16(kf0, qf[0], z);
        z = mfma16(kf1, qf[1], z);
        st[ni] = z;
      }
      __builtin_amdgcn_s_setprio(0);

      const bool diag = (kt == qt);
      const bool needcm = (mrow[kt * 64 + 63] == 0.f);
      if (diag || needcm) {
#pragma unroll
        for (int ni = 0; ni < 4; ++ni)
#pragma unroll
          for (int r = 0; r < 4; ++r) {
            int jin = ni * 16 + lg * 4 + r;
            bool bad = (diag && jin > wq * 16 + lr) ||
                       (needcm && mrow[kt * 64 + jin] == 0.f);
            if (bad) st[ni][r] = -3.402823466e38f;
          }
      }

      float pmax = -3.402823466e38f;
#pragma unroll
      for (int ni = 0; ni < 4; ++ni)
#pragma unroll
        for (int r = 0; r < 4; ++r) pmax = fmaxf(pmax, st[ni][r]);
      pmax = fmaxf(pmax, __shfl_xor(pmax, 16));
      pmax = fmaxf(pmax, __shfl_xor(pmax, 32));

      if (!__all(pmax - mrun <= 8.f)) {   // defer-max (T13)
        float newm = fmaxf(mrun, pmax);
        float alpha = fastexp(mrun - newm);
        lrun *= alpha;
        mrun = newm;
#pragma unroll
        for (int rr = 0; rr < 4; ++rr) {
          float a = __shfl(alpha, lg * 4 + rr, 16);
#pragma unroll
          for (int g = 0; g < 4; ++g) oacc[g][rr] *= a;
        }
      }

      float p[4][4];
      float rs = 0.f;
#pragma unroll
      for (int ni = 0; ni < 4; ++ni)
#pragma unroll
        for (int r = 0; r < 4; ++r) {
          float pv = fastexp(st[ni][r] - mrun);
          p[ni][r] = pv;
          rs += pv;
        }
      rs += __shfl_xor(rs, 16);
      rs += __shfl_xor(rs, 32);
      lrun += rs;

#pragma unroll
      for (int ni = 0; ni < 4; ++ni)
#pragma unroll
        for (int rp = 0; rp < 2; ++rp) {
          unsigned lo = bf16bits(p[ni][2 * rp]);
          unsigned hi = bf16bits(p[ni][2 * rp + 1]);
          *reinterpret_cast<unsigned*>(
              pbase + swz(lr * 128 + ni * 32 + lg * 8 + rp * 4)) = lo | (hi << 16);
        }
      asm volatile("s_waitcnt lgkmcnt(0)" ::: "memory");

      __builtin_amdgcn_s_setprio(1);
#pragma unroll
      for (int c = 0; c < 2; ++c) {
        short8 pa = *reinterpret_cast<const short8*>(
            pbase + swz(lr * 128 + c * 64 + lg * 16));
#pragma unroll
        for (int g = 0; g < 4; ++g) {
          short8 vf = *reinterpret_cast<const short8*>(
              lv + swz((g * 16 + lr) * 128 + c * 64 + lg * 16));
          oacc[g] = mfma16(pa, vf, oacc[g]);
        }
      }
      __builtin_amdgcn_s_setprio(0);
    }
  }

  // ---- merge the two KV-half partials via LDS (reuse lsK region) ----
  __syncthreads();
  float* mO  = reinterpret_cast<float*>(lsK);            // [wq][16 q][64 d]
  float* mML = reinterpret_cast<float*>(lsK + 4 * 4096); // [wq][16 q][2]
  if (hf == 1) {
#pragma unroll
    for (int g = 0; g < 4; ++g)
#pragma unroll
      for (int rr = 0; rr < 4; ++rr)
        mO[wq * 1024 + (lg * 4 + rr) * 64 + g * 16 + lr] = oacc[g][rr];
    if (lg == 0) {
      mML[wq * 32 + lr * 2]     = mrun;
      mML[wq * 32 + lr * 2 + 1] = lrun;
    }
  }
  __syncthreads();
  if (hf == 0) {
    float m1 = mML[wq * 32 + lr * 2];
    float l1 = mML[wq * 32 + lr * 2 + 1];
    float M  = fmaxf(mrun, m1);
    float a0 = fastexp(mrun - M);
    float a1 = fastexp(m1 - M);
    float L  = a0 * lrun + a1 * l1;
#pragma unroll
    for (int rr = 0; rr < 4; ++rr) {
      int qrow = lg * 4 + rr;
      float a0r = __shfl(a0, qrow, 16);
      float a1r = __shfl(a1, qrow, 16);
      float Lr  = __shfl(L,  qrow, 16);
      float inv = 1.0f / Lr;
      int t = qrow0 + qrow;
#pragma unroll
      for (int g = 0; g < 4; ++g) {
        float o = a0r * oacc[g][rr] +
                  a1r * mO[wq * 1024 + qrow * 64 + g * 16 + lr];
        ao[((long)(b * T_ + t)) * D_ + h * 64 + g * 16 + lr] = bf16bits(o * inv);
      }
    }
  }
}

// ---------------------------------------------------------------------------
extern "C" void kernel_launch(void* const* d_in, const int* in_sizes, int n_in,
                              void* d_out, int out_size, void* d_ws,
                              size_t ws_size, hipStream_t stream) {
  const float* x    = (const float*)d_in[0];
  const float* msk  = (const float*)d_in[1];   // (B,T,1)
  const float* wqkv = (const float*)d_in[2];   // (512,1536)
  const float* wout = (const float*)d_in[3];   // (512,512)
  const float* bout = (const float*)d_in[4];   // (512,)
  float* out = (float*)d_out;

  char* ws = (char*)d_ws;
  u16* xb    = (u16*)(ws);                     //  8 MB  x bf16 (8192,512)
  u16* wqkvT = (u16*)(ws + 8388608);           //  1.5MB (1536,512)
  u16* woutT = (u16*)(ws + 9961472);           //  0.5MB (512,512)
  u16* qbuf  = (u16*)(ws + 10485760);          //  8 MB  (B,H,T,DH) scaled
  u16* kbuf  = (u16*)(ws + 18874368);          //  8 MB  (B,H,T,DH)
  u16* vtbuf = (u16*)(ws + 27262976);          //  8 MB  (B,H,DH,T)
  u16* ao    = (u16*)(ws + 35651584);          //  8 MB  (B,T,D)

  prep_kernel<<<1024, 256, 0, stream>>>(x, wqkv, wout, xb, wqkvT, woutT);
  gemm256_kernel<<<(N3D_ / 256) * (BT_ / 256), 512, 0, stream>>>(
      xb, wqkvT, qbuf, kbuf, vtbuf);
  attn_kernel<<<dim3(B_ * H_, T_ / 64), 512, 0, stream>>>(
      qbuf, kbuf, vtbuf, msk, ao);
  gemm_kernel<<<(D_ / 128) * (BT_ / 128), 256, 0, stream>>>(
      ao, woutT, bout, msk, out);
}